// Round 15
// baseline (191.103 us; speedup 1.0000x reference)
//
#include <hip/hip_runtime.h>

#define DIM 256
#define NA 16
#define NE 4
#define KTOT 288   // 16 atoms + 256 latent + 16 zero pad

typedef __attribute__((ext_vector_type(8))) short short8;
typedef __attribute__((ext_vector_type(4))) short short4v;
typedef __attribute__((ext_vector_type(4))) float f32x4;
typedef __attribute__((ext_vector_type(2))) unsigned int uint2v;

static __device__ __forceinline__ ushort f2bf(float f) {
  union { float f; unsigned int u; } v; v.f = f;
  unsigned int r = (v.u + 0x7FFFu + ((v.u >> 16) & 1u)) >> 16;
  return (ushort)r;
}

static __device__ __forceinline__ float bf2f(ushort s) {
  union { unsigned int u; float f; } v; v.u = ((unsigned int)s) << 16;
  return v.f;
}

static __device__ __forceinline__ unsigned cvtpk(float lo, float hi) {
  unsigned r;
  asm("v_cvt_pk_bf16_f32 %0, %1, %2" : "=v"(r) : "v"(lo), "v"(hi));
  return r;
}

// async global->LDS DMA, 16B per lane; lds dest wave-uniform (HW adds lane*16)
static __device__ __forceinline__ void gll16(const void* g, void* l) {
  __builtin_amdgcn_global_load_lds((const __attribute__((address_space(1))) void*)g,
                                   (__attribute__((address_space(3))) void*)l, 16, 0, 0);
}

// ---------------- prep 1: h = relu(latent@W1+b1)@W2+b2 ; build G = [atoms|h|0] bf16
__global__ __launch_bounds__(256) void prep_h_kernel(
    const float* __restrict__ latent, const float* __restrict__ atoms,
    const float* __restrict__ W1, const float* __restrict__ b1,
    const float* __restrict__ W2, const float* __restrict__ b2,
    float* __restrict__ h_out, ushort* __restrict__ G_out) {
  __shared__ float lat[8][DIM];
  __shared__ float t1[8][DIM];
  const int b = blockIdx.x >> 5, i0 = (blockIdx.x & 31) * 8;
  const int k = threadIdx.x;
  #pragma unroll
  for (int r = 0; r < 8; ++r) lat[r][k] = latent[(b*256 + i0 + r) * DIM + k];
  __syncthreads();
  float acc[8];
  #pragma unroll
  for (int r = 0; r < 8; ++r) acc[r] = b1[k];
  for (int c = 0; c < DIM; c += 4) {
    float w0 = W1[(c+0)*DIM + k], w1 = W1[(c+1)*DIM + k];
    float w2 = W1[(c+2)*DIM + k], w3 = W1[(c+3)*DIM + k];
    #pragma unroll
    for (int r = 0; r < 8; ++r) {
      const float4 l4 = *reinterpret_cast<const float4*>(&lat[r][c]);
      acc[r] += l4.x*w0 + l4.y*w1 + l4.z*w2 + l4.w*w3;
    }
  }
  #pragma unroll
  for (int r = 0; r < 8; ++r) t1[r][k] = fmaxf(acc[r], 0.f);
  __syncthreads();
  #pragma unroll
  for (int r = 0; r < 8; ++r) acc[r] = b2[k];
  for (int c = 0; c < DIM; c += 4) {
    float w0 = W2[(c+0)*DIM + k], w1 = W2[(c+1)*DIM + k];
    float w2 = W2[(c+2)*DIM + k], w3 = W2[(c+3)*DIM + k];
    #pragma unroll
    for (int r = 0; r < 8; ++r) {
      const float4 l4 = *reinterpret_cast<const float4*>(&t1[r][c]);
      acc[r] += l4.x*w0 + l4.y*w1 + l4.z*w2 + l4.w*w3;
    }
  }
  #pragma unroll
  for (int r = 0; r < 8; ++r) {
    int row = b*256 + i0 + r;
    h_out[row*DIM + k] = acc[r];
    G_out[row*KTOT + NA + k] = f2bf(acc[r]);
  }
  if (k < NA) {
    #pragma unroll
    for (int r = 0; r < 8; ++r) {
      int row = b*256 + i0 + r;
      G_out[row*KTOT + k] = f2bf(atoms[row*NA + k]);
      G_out[row*KTOT + 272 + k] = 0;
    }
  }
}

// ---------------- prep 2: W3T[n][c] = bf16(W3[1+c][n]) zero-padded to 288
__global__ __launch_bounds__(256) void prep_w3t_kernel(
    const float* __restrict__ W3, ushort* __restrict__ W3T) {
  const int kk = blockIdx.x, c = threadIdx.x;
  W3T[kk*KTOT + c] = (c < 272) ? f2bf(W3[(1+c)*DIM + kk]) : (ushort)0;
  if (c < 32) {
    int c2 = 256 + c;
    W3T[kk*KTOT + c2] = (c2 < 272) ? f2bf(W3[(1+c2)*DIM + kk]) : (ushort)0;
  }
}

// ---------------- main: one WG per (b, it<=jt, quarter) = 8*136*4 = 4352 WGs.
// Quarter pair-tile: 64 pairs (4 i-rows x 16 j-rows) x 256 n x K288.
// acc[4][2] = 32 AGPR -> <=128 regs/wave -> 4 waves/SIMD = 2 WGs/CU co-resident:
// one WG's barrier/DMA waits hide under the other's compute (the R13 stall).
// A = W3T (raw DMA), B = y[pair][c] = G[i][c]*G[j][c] (4 products/thread/chunk).
__global__ __attribute__((amdgpu_flat_work_group_size(512,512), amdgpu_waves_per_eu(4,4)))
void edge_main_kernel(
    const float* __restrict__ positions,
    const float* __restrict__ W3, const float* __restrict__ b3,
    const float* __restrict__ W4, const float* __restrict__ b4,
    const ushort* __restrict__ G, const ushort* __restrict__ W3T,
    float* __restrict__ out) {
  __shared__ union UU {
    char w3t[2][16384];           // A-operand chunk dbuf (16 ntiles x 1KB)
    float partial[4][64][4];      // epilogue partials (4KB), after final barrier
  } u;
  __shared__ char y_lds[2][4096]; // B-operand chunk dbuf (4 ptiles x 1KB)
  __shared__ float dist_lds[64];

  const int bid = blockIdx.x;
  const int b = bid / 544;
  int rem = bid - b*544;
  const int wg4 = rem & 3;            // pair-quarter: i-rows [wg4*4, wg4*4+4)
  int q = rem >> 2;
  int it = 0;
  while (q >= 16 - it) { q -= 16 - it; ++it; }
  const int jt = it + q;
  const int i0 = b*256 + it*16, j0 = b*256 + jt*16;
  const int pbase = wg4*4;

  const int tid = threadIdx.x;
  const int lane = tid & 63, w = tid >> 6;
  const int wn = w & 3;      // n-group: ntiles wn*4 .. +4
  const int wp = w >> 2;     // pair-group: ptiles wp*2 .. +2
  const int c15 = lane & 15, hi = lane >> 4;

  // ---- prologue: dist for the 64 pairs of this quarter
  if (tid < 64) {
    int pi = tid >> 4, pj = tid & 15;
    const float* pa = &positions[(i0 + pbase + pi)*3];
    const float* pb = &positions[(j0 + pj)*3];
    float dx = pa[0]-pb[0], dy = pa[1]-pb[1], dz = pa[2]-pb[2];
    float d2 = dx*dx + dy*dy + dz*dz;
    dist_lds[tid] = d2 > 0.f ? sqrtf(d2) : 0.f;
  }

  // ---- stage W3T chunk kk (16KB = 64 subtiles of 256B), identical to R13
  auto stage = [&](int kk) {
    #pragma unroll
    for (int qq = 0; qq < 2; ++qq) {
      int s0 = w*8 + qq*4;                  // wave-uniform base subtile
      int sub = s0 + hi;
      int nt_ = sub >> 2, oct = sub & 3;
      const ushort* src = &W3T[(size_t)(nt_*16 + c15)*KTOT + kk*32 + oct*8];
      gll16(src, u.w3t[kk & 1] + s0*256);   // + lane*16 implicit
    }
  };

  // ---- y-build: thread owns (pair pr = tid>>3, col-quad s = tid&7)
  const int pr = tid >> 3, s = tid & 7;
  const int pi_ = pr >> 4, pj_ = pr & 15;
  const ushort* giRow = &G[(size_t)(i0 + pbase + pi_)*KTOT + s*4];
  const ushort* gjRow = &G[(size_t)(j0 + pj_)*KTOT + s*4];

  short4v yi, yj;
  auto y_load = [&](int kk) {               // 2x 8B loads, issued early
    yi = *reinterpret_cast<const short4v*>(giRow + kk*32);
    yj = *reinterpret_cast<const short4v*>(gjRow + kk*32);
  };
  auto y_finish = [&](int kk) {             // 4 muls + 2 cvtpk + 8B ds_write
    union { ushort us[4]; short4v s4; } A, B;
    A.s4 = yi; B.s4 = yj;
    uint2v p;
    p.x = cvtpk(bf2f(A.us[0])*bf2f(B.us[0]), bf2f(A.us[1])*bf2f(B.us[1]));
    p.y = cvtpk(bf2f(A.us[2])*bf2f(B.us[2]), bf2f(A.us[3])*bf2f(B.us[3]));
    char* dst = y_lds[kk & 1] + pi_*1024 + (s >> 1)*256 + pj_*16 + (s & 1)*8;
    *reinterpret_cast<uint2v*>(dst) = p;
  };

  f32x4 acc[4][2];
  #pragma unroll
  for (int at = 0; at < 4; ++at)
    #pragma unroll
    for (int bt = 0; bt < 2; ++bt) { acc[at][bt].x=0.f; acc[at][bt].y=0.f; acc[at][bt].z=0.f; acc[at][bt].w=0.f; }

  stage(0);
  y_load(0);
  y_finish(0);
  __syncthreads();   // stage(0) DMA drained; y(0) + dist visible

  #pragma unroll
  for (int kk = 0; kk < 9; ++kk) {
    if (kk < 8) { y_load(kk + 1); stage(kk + 1); }     // into opposite buffers
    // ---- MFMA chunk kk: 4 A-frags + 2 B-frags, 8 MFMA
    {
      const char* ap = u.w3t[kk & 1];
      const char* bp = y_lds[kk & 1];
      short8 afr[4];
      #pragma unroll
      for (int at = 0; at < 4; ++at)
        afr[at] = *reinterpret_cast<const short8*>(ap + (wn*4 + at)*1024 + lane*16);
      #pragma unroll
      for (int bt = 0; bt < 2; ++bt) {
        short8 bb = *reinterpret_cast<const short8*>(bp + (wp*2 + bt)*1024 + lane*16);
        acc[0][bt] = __builtin_amdgcn_mfma_f32_16x16x32_bf16(afr[0], bb, acc[0][bt], 0, 0, 0);
        acc[1][bt] = __builtin_amdgcn_mfma_f32_16x16x32_bf16(afr[1], bb, acc[1][bt], 0, 0, 0);
        acc[2][bt] = __builtin_amdgcn_mfma_f32_16x16x32_bf16(afr[2], bb, acc[2][bt], 0, 0, 0);
        acc[3][bt] = __builtin_amdgcn_mfma_f32_16x16x32_bf16(afr[3], bb, acc[3][bt], 0, 0, 0);
      }
    }
    if (kk < 8) y_finish(kk + 1);                      // writes other y buffer
    __syncthreads();   // drains stage DMA; y writes visible; frees kk bufs
  }

  __builtin_amdgcn_sched_barrier(0);   // keep epilogue loads out of K-loop region

  // ---- epilogue: z = acc + dist*w30 + b3 ; relu ; x W4 (256n -> 4)
  float b3v[4][4], w30v[4][4]; float4 w4v[4][4];
  #pragma unroll
  for (int at = 0; at < 4; ++at)
    #pragma unroll
    for (int r = 0; r < 4; ++r) {
      int n = (wn*4 + at)*16 + hi*4 + r;
      b3v[at][r]  = b3[n];
      w30v[at][r] = W3[n];                 // W3 row 0 = dist weights
      w4v[at][r]  = *reinterpret_cast<const float4*>(&W4[n*4]);
    }
  #pragma unroll
  for (int bt = 0; bt < 2; ++bt) {
    int pair = (wp*2 + bt)*16 + c15;
    float d = dist_lds[pair];
    float4 pe; pe.x=0.f; pe.y=0.f; pe.z=0.f; pe.w=0.f;
    #pragma unroll
    for (int at = 0; at < 4; ++at)
      #pragma unroll
      for (int r = 0; r < 4; ++r) {
        float z  = acc[at][bt][r] + d*w30v[at][r] + b3v[at][r];
        float rz = fmaxf(z, 0.f);
        pe.x += rz*w4v[at][r].x; pe.y += rz*w4v[at][r].y;
        pe.z += rz*w4v[at][r].z; pe.w += rz*w4v[at][r].w;
      }
    // reduce over hi (n-quarters within this wave)
    pe.x += __shfl_xor(pe.x, 16); pe.y += __shfl_xor(pe.y, 16);
    pe.z += __shfl_xor(pe.z, 16); pe.w += __shfl_xor(pe.w, 16);
    pe.x += __shfl_xor(pe.x, 32); pe.y += __shfl_xor(pe.y, 32);
    pe.z += __shfl_xor(pe.z, 32); pe.w += __shfl_xor(pe.w, 32);
    if (hi == 0) *reinterpret_cast<float4*>(&u.partial[wn][pair][0]) = pe;
  }
  __syncthreads();
  if (tid < 64) {
    int pair = tid;
    float4 v;
    v.x = u.partial[0][pair][0] + u.partial[1][pair][0] + u.partial[2][pair][0] + u.partial[3][pair][0];
    v.y = u.partial[0][pair][1] + u.partial[1][pair][1] + u.partial[2][pair][1] + u.partial[3][pair][1];
    v.z = u.partial[0][pair][2] + u.partial[1][pair][2] + u.partial[2][pair][2] + u.partial[3][pair][2];
    v.w = u.partial[0][pair][3] + u.partial[1][pair][3] + u.partial[2][pair][3] + u.partial[3][pair][3];
    const float4 bv = *reinterpret_cast<const float4*>(b4);
    v.x += bv.x; v.y += bv.y; v.z += bv.z; v.w += bv.w;
    int il = it*16 + pbase + (pair >> 4);   // local i row
    int jl = jt*16 + (pair & 15);           // local j row
    *reinterpret_cast<float4*>(&out[(((size_t)b*256 + il)*256 + jl)*NE]) = v;
    if (it != jt)
      *reinterpret_cast<float4*>(&out[(((size_t)b*256 + jl)*256 + il)*NE]) = v;
  }
}

extern "C" void kernel_launch(void* const* d_in, const int* in_sizes, int n_in,
                              void* d_out, int out_size, void* d_ws, size_t ws_size,
                              hipStream_t stream) {
  const float* latent    = (const float*)d_in[0];
  const float* positions = (const float*)d_in[1];
  const float* atoms     = (const float*)d_in[2];
  const float* W1 = (const float*)d_in[3];
  const float* b1 = (const float*)d_in[4];
  const float* W2 = (const float*)d_in[5];
  const float* b2 = (const float*)d_in[6];
  const float* W3 = (const float*)d_in[7];
  const float* b3 = (const float*)d_in[8];
  const float* W4 = (const float*)d_in[9];
  const float* b4 = (const float*)d_in[10];
  float* out = (float*)d_out;

  char* ws = (char*)d_ws;
  float*  h_ws   = (float*)ws;                          // 8*256*256*4   = 2,097,152 B
  ushort* G_ws   = (ushort*)(ws + 2097152);             // 8*256*288*2   = 1,179,648 B
  ushort* W3T_ws = (ushort*)(ws + 2097152 + 1179648);   // 256*288*2     =   147,456 B

  hipLaunchKernelGGL(prep_h_kernel, dim3(256), dim3(256), 0, stream,
                     latent, atoms, W1, b1, W2, b2, h_ws, G_ws);
  hipLaunchKernelGGL(prep_w3t_kernel, dim3(256), dim3(256), 0, stream, W3, W3T_ws);
  hipLaunchKernelGGL(edge_main_kernel, dim3(4352), dim3(512), 0, stream,
                     positions, W3, b3, W4, b4, G_ws, W3T_ws, out);
}

// Round 16
// 146.287 us; speedup vs baseline: 1.3064x; 1.3064x over previous
//
#include <hip/hip_runtime.h>

#define DIM 256
#define NA 16
#define NE 4
#define KTOT 288   // 16 atoms + 256 latent + 16 zero pad

typedef __attribute__((ext_vector_type(8))) short short8;
typedef __attribute__((ext_vector_type(4))) float f32x4;

static __device__ __forceinline__ ushort f2bf(float f) {
  union { float f; unsigned int u; } v; v.f = f;
  unsigned int r = (v.u + 0x7FFFu + ((v.u >> 16) & 1u)) >> 16;
  return (ushort)r;
}

static __device__ __forceinline__ float bf2f(ushort s) {
  union { unsigned int u; float f; } v; v.u = ((unsigned int)s) << 16;
  return v.f;
}

static __device__ __forceinline__ unsigned cvtpk(float lo, float hi) {
  unsigned r;
  asm("v_cvt_pk_bf16_f32 %0, %1, %2" : "=v"(r) : "v"(lo), "v"(hi));
  return r;
}

// async global->LDS DMA, 16B per lane; lds dest wave-uniform (HW adds lane*16)
static __device__ __forceinline__ void gll16(const void* g, void* l) {
  __builtin_amdgcn_global_load_lds((const __attribute__((address_space(1))) void*)g,
                                   (__attribute__((address_space(3))) void*)l, 16, 0, 0);
}

// ---------------- prep 1: h = relu(latent@W1+b1)@W2+b2 ; build G = [atoms|h|0] bf16
__global__ __launch_bounds__(256) void prep_h_kernel(
    const float* __restrict__ latent, const float* __restrict__ atoms,
    const float* __restrict__ W1, const float* __restrict__ b1,
    const float* __restrict__ W2, const float* __restrict__ b2,
    float* __restrict__ h_out, ushort* __restrict__ G_out) {
  __shared__ float lat[8][DIM];
  __shared__ float t1[8][DIM];
  const int b = blockIdx.x >> 5, i0 = (blockIdx.x & 31) * 8;
  const int k = threadIdx.x;
  #pragma unroll
  for (int r = 0; r < 8; ++r) lat[r][k] = latent[(b*256 + i0 + r) * DIM + k];
  __syncthreads();
  float acc[8];
  #pragma unroll
  for (int r = 0; r < 8; ++r) acc[r] = b1[k];
  for (int c = 0; c < DIM; c += 4) {
    float w0 = W1[(c+0)*DIM + k], w1 = W1[(c+1)*DIM + k];
    float w2 = W1[(c+2)*DIM + k], w3 = W1[(c+3)*DIM + k];
    #pragma unroll
    for (int r = 0; r < 8; ++r) {
      const float4 l4 = *reinterpret_cast<const float4*>(&lat[r][c]);
      acc[r] += l4.x*w0 + l4.y*w1 + l4.z*w2 + l4.w*w3;
    }
  }
  #pragma unroll
  for (int r = 0; r < 8; ++r) t1[r][k] = fmaxf(acc[r], 0.f);
  __syncthreads();
  #pragma unroll
  for (int r = 0; r < 8; ++r) acc[r] = b2[k];
  for (int c = 0; c < DIM; c += 4) {
    float w0 = W2[(c+0)*DIM + k], w1 = W2[(c+1)*DIM + k];
    float w2 = W2[(c+2)*DIM + k], w3 = W2[(c+3)*DIM + k];
    #pragma unroll
    for (int r = 0; r < 8; ++r) {
      const float4 l4 = *reinterpret_cast<const float4*>(&t1[r][c]);
      acc[r] += l4.x*w0 + l4.y*w1 + l4.z*w2 + l4.w*w3;
    }
  }
  #pragma unroll
  for (int r = 0; r < 8; ++r) {
    int row = b*256 + i0 + r;
    h_out[row*DIM + k] = acc[r];
    G_out[row*KTOT + NA + k] = f2bf(acc[r]);
  }
  if (k < NA) {
    #pragma unroll
    for (int r = 0; r < 8; ++r) {
      int row = b*256 + i0 + r;
      G_out[row*KTOT + k] = f2bf(atoms[row*NA + k]);
      G_out[row*KTOT + 272 + k] = 0;
    }
  }
}

// ---------------- prep 2: W3T[n][c] = bf16(W3[1+c][n]) zero-padded to 288
__global__ __launch_bounds__(256) void prep_w3t_kernel(
    const float* __restrict__ W3, ushort* __restrict__ W3T) {
  const int kk = blockIdx.x, c = threadIdx.x;
  W3T[kk*KTOT + c] = (c < 272) ? f2bf(W3[(1+c)*DIM + kk]) : (ushort)0;
  if (c < 32) {
    int c2 = 256 + c;
    W3T[kk*KTOT + c2] = (c2 < 272) ? f2bf(W3[(1+c2)*DIM + kk]) : (ushort)0;
  }
}

// ---------------- main: one WG per (b, it<=jt, half) = 8*136*2 = 2176 WGs.
// Half pair-tile: 128 pairs (8 i-rows x 16 j-rows) x 256 n x K288.
// acc[4][4] = 64 AGPR; in-loop ~112 regs, epilogue capped ~104 via per-at
// constant loading -> fits waves_per_eu(4,4) budget: 4 waves/SIMD = 2 WGs/CU.
// A = W3T (raw DMA), B = y[pair][c] = G[i][c]*G[j][c] (8 products/thread/chunk).
__global__ __attribute__((amdgpu_flat_work_group_size(512,512), amdgpu_waves_per_eu(4,4)))
void edge_main_kernel(
    const float* __restrict__ positions,
    const float* __restrict__ W3, const float* __restrict__ b3,
    const float* __restrict__ W4, const float* __restrict__ b4,
    const ushort* __restrict__ G, const ushort* __restrict__ W3T,
    float* __restrict__ out) {
  __shared__ union UU {
    char w3t[2][16384];           // A-operand chunk dbuf (16 ntiles x 1KB)
    float partial[4][128][4];     // epilogue partials (8KB), after final barrier
  } u;
  __shared__ char y_lds[2][8192]; // B-operand chunk dbuf (8 ptiles x 1KB)
  __shared__ float dist_lds[128];

  const int bid = blockIdx.x;
  const int b = bid / 272;
  int rem = bid - b*272;
  const int hh = rem & 1;             // i-half: rows [hh*8, hh*8+8) of the tile
  int q = rem >> 1;
  int it = 0;
  while (q >= 16 - it) { q -= 16 - it; ++it; }
  const int jt = it + q;
  const int i0 = b*256 + it*16 + hh*8, j0 = b*256 + jt*16;

  const int tid = threadIdx.x;
  const int lane = tid & 63, w = tid >> 6;
  const int wn = w & 3;      // n-group: ntiles wn*4 .. +4
  const int wp = w >> 2;     // pair-group: ptiles wp*4 .. +4
  const int c15 = lane & 15, hi = lane >> 4;

  // ---- prologue: dist for the 128 pairs of this half
  if (tid < 128) {
    int pi = tid >> 4, pj = tid & 15;
    const float* pa = &positions[(i0 + pi)*3];
    const float* pb = &positions[(j0 + pj)*3];
    float dx = pa[0]-pb[0], dy = pa[1]-pb[1], dz = pa[2]-pb[2];
    float d2 = dx*dx + dy*dy + dz*dz;
    dist_lds[tid] = d2 > 0.f ? sqrtf(d2) : 0.f;
  }

  // ---- stage W3T chunk kk (16KB = 64 subtiles of 256B), identical to R13
  auto stage = [&](int kk) {
    #pragma unroll
    for (int qq = 0; qq < 2; ++qq) {
      int s0 = w*8 + qq*4;                  // wave-uniform base subtile
      int sub = s0 + hi;
      int nt_ = sub >> 2, oct = sub & 3;
      const ushort* src = &W3T[(size_t)(nt_*16 + c15)*KTOT + kk*32 + oct*8];
      gll16(src, u.w3t[kk & 1] + s0*256);   // + lane*16 implicit
    }
  };

  // ---- y-build: thread owns (pair pr = tid>>2, octet so = tid&3); 8 cols
  const int pr = tid >> 2, so = tid & 3;
  const int pi_ = pr >> 4, pj_ = pr & 15;   // pi_ in 0..7 (i-row of half)
  const ushort* giRow = &G[(size_t)(i0 + pi_)*KTOT + so*8];
  const ushort* gjRow = &G[(size_t)(j0 + pj_)*KTOT + so*8];

  short8 yi, yj;
  auto y_load = [&](int kk) {               // 2x 16B loads, issued early
    yi = *reinterpret_cast<const short8*>(giRow + kk*32);
    yj = *reinterpret_cast<const short8*>(gjRow + kk*32);
  };
  auto y_finish = [&](int kk) {             // 8 muls + 4 cvtpk + 16B ds_write
    union { ushort us[8]; short8 s8; } A, B;
    A.s8 = yi; B.s8 = yj;
    uint4 p;
    p.x = cvtpk(bf2f(A.us[0])*bf2f(B.us[0]), bf2f(A.us[1])*bf2f(B.us[1]));
    p.y = cvtpk(bf2f(A.us[2])*bf2f(B.us[2]), bf2f(A.us[3])*bf2f(B.us[3]));
    p.z = cvtpk(bf2f(A.us[4])*bf2f(B.us[4]), bf2f(A.us[5])*bf2f(B.us[5]));
    p.w = cvtpk(bf2f(A.us[6])*bf2f(B.us[6]), bf2f(A.us[7])*bf2f(B.us[7]));
    char* dst = y_lds[kk & 1] + pi_*1024 + so*256 + pj_*16;
    *reinterpret_cast<uint4*>(dst) = p;
  };

  f32x4 acc[4][4];
  #pragma unroll
  for (int at = 0; at < 4; ++at)
    #pragma unroll
    for (int bt = 0; bt < 4; ++bt) { acc[at][bt].x=0.f; acc[at][bt].y=0.f; acc[at][bt].z=0.f; acc[at][bt].w=0.f; }

  stage(0);
  y_load(0);
  y_finish(0);
  __syncthreads();   // stage(0) DMA drained; y(0) + dist visible

  #pragma unroll
  for (int kk = 0; kk < 9; ++kk) {
    if (kk < 8) { y_load(kk + 1); stage(kk + 1); }     // into opposite buffers
    // ---- MFMA chunk kk: 4 A-frags + 4 B-frags, 16 MFMA
    {
      const char* ap = u.w3t[kk & 1];
      const char* bp = y_lds[kk & 1];
      short8 afr[4];
      #pragma unroll
      for (int at = 0; at < 4; ++at)
        afr[at] = *reinterpret_cast<const short8*>(ap + (wn*4 + at)*1024 + lane*16);
      #pragma unroll
      for (int bt = 0; bt < 4; ++bt) {
        short8 bb = *reinterpret_cast<const short8*>(bp + (wp*4 + bt)*1024 + lane*16);
        acc[0][bt] = __builtin_amdgcn_mfma_f32_16x16x32_bf16(afr[0], bb, acc[0][bt], 0, 0, 0);
        acc[1][bt] = __builtin_amdgcn_mfma_f32_16x16x32_bf16(afr[1], bb, acc[1][bt], 0, 0, 0);
        acc[2][bt] = __builtin_amdgcn_mfma_f32_16x16x32_bf16(afr[2], bb, acc[2][bt], 0, 0, 0);
        acc[3][bt] = __builtin_amdgcn_mfma_f32_16x16x32_bf16(afr[3], bb, acc[3][bt], 0, 0, 0);
      }
    }
    if (kk < 8) y_finish(kk + 1);                      // writes other y buffer
    __syncthreads();   // drains stage DMA; y writes visible; frees kk bufs
  }

  __builtin_amdgcn_sched_barrier(0);   // keep epilogue loads out of K-loop region

  // ---- epilogue: per-at constant loading to cap register pressure.
  // pe[bt] accumulates the 4 outputs for each of this lane's 4 pairs.
  float4 pe[4];
  #pragma unroll
  for (int bt = 0; bt < 4; ++bt) { pe[bt].x=0.f; pe[bt].y=0.f; pe[bt].z=0.f; pe[bt].w=0.f; }
  #pragma unroll
  for (int at = 0; at < 4; ++at) {
    float b3v[4], w30v[4]; float4 w4v[4];
    #pragma unroll
    for (int r = 0; r < 4; ++r) {
      int n = (wn*4 + at)*16 + hi*4 + r;
      b3v[r]  = b3[n];
      w30v[r] = W3[n];                 // W3 row 0 = dist weights
      w4v[r]  = *reinterpret_cast<const float4*>(&W4[n*4]);
    }
    #pragma unroll
    for (int bt = 0; bt < 4; ++bt) {
      float d = dist_lds[(wp*4 + bt)*16 + c15];
      #pragma unroll
      for (int r = 0; r < 4; ++r) {
        float z  = acc[at][bt][r] + d*w30v[r] + b3v[r];
        float rz = fmaxf(z, 0.f);
        pe[bt].x += rz*w4v[r].x; pe[bt].y += rz*w4v[r].y;
        pe[bt].z += rz*w4v[r].z; pe[bt].w += rz*w4v[r].w;
      }
    }
  }
  #pragma unroll
  for (int bt = 0; bt < 4; ++bt) {
    int pair = (wp*4 + bt)*16 + c15;
    float4 p = pe[bt];
    p.x += __shfl_xor(p.x, 16); p.y += __shfl_xor(p.y, 16);
    p.z += __shfl_xor(p.z, 16); p.w += __shfl_xor(p.w, 16);
    p.x += __shfl_xor(p.x, 32); p.y += __shfl_xor(p.y, 32);
    p.z += __shfl_xor(p.z, 32); p.w += __shfl_xor(p.w, 32);
    if (hi == 0) *reinterpret_cast<float4*>(&u.partial[wn][pair][0]) = p;
  }
  __syncthreads();
  if (tid < 128) {
    int pair = tid;
    float4 v;
    v.x = u.partial[0][pair][0] + u.partial[1][pair][0] + u.partial[2][pair][0] + u.partial[3][pair][0];
    v.y = u.partial[0][pair][1] + u.partial[1][pair][1] + u.partial[2][pair][1] + u.partial[3][pair][1];
    v.z = u.partial[0][pair][2] + u.partial[1][pair][2] + u.partial[2][pair][2] + u.partial[3][pair][2];
    v.w = u.partial[0][pair][3] + u.partial[1][pair][3] + u.partial[2][pair][3] + u.partial[3][pair][3];
    const float4 bv = *reinterpret_cast<const float4*>(b4);
    v.x += bv.x; v.y += bv.y; v.z += bv.z; v.w += bv.w;
    int il = it*16 + hh*8 + (pair >> 4);    // local i row
    int jl = jt*16 + (pair & 15);           // local j row
    *reinterpret_cast<float4*>(&out[(((size_t)b*256 + il)*256 + jl)*NE]) = v;
    if (it != jt)
      *reinterpret_cast<float4*>(&out[(((size_t)b*256 + jl)*256 + il)*NE]) = v;
  }
}

extern "C" void kernel_launch(void* const* d_in, const int* in_sizes, int n_in,
                              void* d_out, int out_size, void* d_ws, size_t ws_size,
                              hipStream_t stream) {
  const float* latent    = (const float*)d_in[0];
  const float* positions = (const float*)d_in[1];
  const float* atoms     = (const float*)d_in[2];
  const float* W1 = (const float*)d_in[3];
  const float* b1 = (const float*)d_in[4];
  const float* W2 = (const float*)d_in[5];
  const float* b2 = (const float*)d_in[6];
  const float* W3 = (const float*)d_in[7];
  const float* b3 = (const float*)d_in[8];
  const float* W4 = (const float*)d_in[9];
  const float* b4 = (const float*)d_in[10];
  float* out = (float*)d_out;

  char* ws = (char*)d_ws;
  float*  h_ws   = (float*)ws;                          // 8*256*256*4   = 2,097,152 B
  ushort* G_ws   = (ushort*)(ws + 2097152);             // 8*256*288*2   = 1,179,648 B
  ushort* W3T_ws = (ushort*)(ws + 2097152 + 1179648);   // 256*288*2     =   147,456 B

  hipLaunchKernelGGL(prep_h_kernel, dim3(256), dim3(256), 0, stream,
                     latent, atoms, W1, b1, W2, b2, h_ws, G_ws);
  hipLaunchKernelGGL(prep_w3t_kernel, dim3(256), dim3(256), 0, stream, W3, W3T_ws);
  hipLaunchKernelGGL(edge_main_kernel, dim3(2176), dim3(512), 0, stream,
                     positions, W3, b3, W4, b4, G_ws, W3T_ws, out);
}

// Round 17
// 110.269 us; speedup vs baseline: 1.7331x; 1.3266x over previous
//
#include <hip/hip_runtime.h>

#define DIM 256
#define NA 16
#define NE 4
#define KTOT 288   // 16 atoms + 256 latent + 16 zero pad (9 chunks of 32)

typedef __attribute__((ext_vector_type(8))) short short8;
typedef __attribute__((ext_vector_type(4))) float f32x4;

static __device__ __forceinline__ ushort f2bf(float f) {
  union { float f; unsigned int u; } v; v.f = f;
  unsigned int r = (v.u + 0x7FFFu + ((v.u >> 16) & 1u)) >> 16;
  return (ushort)r;
}

static __device__ __forceinline__ float bf2f(ushort s) {
  union { unsigned int u; float f; } v; v.u = ((unsigned int)s) << 16;
  return v.f;
}

static __device__ __forceinline__ unsigned cvtpk(float lo, float hi) {
  unsigned r;
  asm("v_cvt_pk_bf16_f32 %0, %1, %2" : "=v"(r) : "v"(lo), "v"(hi));
  return r;
}

// fragment-major index (ushort units): subtile = 16 rows x 32 cols = 1KB,
// laid out [row-block rb][k-chunk kk][oct][r15][e]:
//   idx = ((rb*9 + kk)*4 + oct)*128 + r15*8 + e
// -> a wave fragment load is base + lane*8 (fully coalesced 1KB).
static __device__ __forceinline__ int fragIdx(int row, int c) {
  return (((row >> 4)*9 + (c >> 5))*4 + ((c >> 3) & 3))*128 + (row & 15)*8 + (c & 7);
}

// ---------------- prep 1: h = relu(latent@W1+b1)@W2+b2 ; Gf = frag-major [atoms|h|0] bf16
__global__ __launch_bounds__(256) void prep_h_kernel(
    const float* __restrict__ latent, const float* __restrict__ atoms,
    const float* __restrict__ W1, const float* __restrict__ b1,
    const float* __restrict__ W2, const float* __restrict__ b2,
    ushort* __restrict__ Gf) {
  __shared__ float lat[8][DIM];
  __shared__ float t1[8][DIM];
  const int b = blockIdx.x >> 5, i0 = (blockIdx.x & 31) * 8;
  const int k = threadIdx.x;
  #pragma unroll
  for (int r = 0; r < 8; ++r) lat[r][k] = latent[(b*256 + i0 + r) * DIM + k];
  __syncthreads();
  float acc[8];
  #pragma unroll
  for (int r = 0; r < 8; ++r) acc[r] = b1[k];
  for (int c = 0; c < DIM; c += 4) {
    float w0 = W1[(c+0)*DIM + k], w1 = W1[(c+1)*DIM + k];
    float w2 = W1[(c+2)*DIM + k], w3 = W1[(c+3)*DIM + k];
    #pragma unroll
    for (int r = 0; r < 8; ++r) {
      const float4 l4 = *reinterpret_cast<const float4*>(&lat[r][c]);
      acc[r] += l4.x*w0 + l4.y*w1 + l4.z*w2 + l4.w*w3;
    }
  }
  #pragma unroll
  for (int r = 0; r < 8; ++r) t1[r][k] = fmaxf(acc[r], 0.f);
  __syncthreads();
  #pragma unroll
  for (int r = 0; r < 8; ++r) acc[r] = b2[k];
  for (int c = 0; c < DIM; c += 4) {
    float w0 = W2[(c+0)*DIM + k], w1 = W2[(c+1)*DIM + k];
    float w2 = W2[(c+2)*DIM + k], w3 = W2[(c+3)*DIM + k];
    #pragma unroll
    for (int r = 0; r < 8; ++r) {
      const float4 l4 = *reinterpret_cast<const float4*>(&t1[r][c]);
      acc[r] += l4.x*w0 + l4.y*w1 + l4.z*w2 + l4.w*w3;
    }
  }
  #pragma unroll
  for (int r = 0; r < 8; ++r) {
    int row = b*256 + i0 + r;
    Gf[fragIdx(row, NA + k)] = f2bf(acc[r]);
  }
  if (k < NA) {
    #pragma unroll
    for (int r = 0; r < 8; ++r) {
      int row = b*256 + i0 + r;
      Gf[fragIdx(row, k)] = f2bf(atoms[row*NA + k]);
      Gf[fragIdx(row, 272 + k)] = 0;
    }
  }
}

// ---------------- prep 2: W3Tf frag-major: value(n,c) = bf16(W3[1+c][n]), pad 0
__global__ __launch_bounds__(256) void prep_w3t_kernel(
    const float* __restrict__ W3, ushort* __restrict__ W3Tf) {
  const int n = blockIdx.x, c = threadIdx.x;
  W3Tf[fragIdx(n, c)] = (c < 272) ? f2bf(W3[(1+c)*DIM + n]) : (ushort)0;
  if (c < 32) {
    int c2 = 256 + c;
    W3Tf[fragIdx(n, c2)] = (c2 < 272) ? f2bf(W3[(1+c2)*DIM + n]) : (ushort)0;
  }
}

// ---------------- main: one WG per (b, it<=jt) pair-tile (1088 WGs, 512 thr).
// BARRIER-FREE K-loop: both MFMA operands come straight from L2.
//   A-frag: W3Tf fragment-major, coalesced 16B/lane.
//   B-frag: built in-register: bb[lane(c15,hi)] = G[i0+ptg][k]*G[j0+c15][k].
// No LDS staging, no DMA, no syncthreads until the epilogue -> the two
// waves/SIMD are never lockstepped; loads schedule freely under 256 regs.
__global__ __attribute__((amdgpu_flat_work_group_size(512,512), amdgpu_waves_per_eu(2,2)))
void edge_main_kernel(
    const float* __restrict__ positions,
    const float* __restrict__ W3, const float* __restrict__ b3,
    const float* __restrict__ W4, const float* __restrict__ b4,
    const ushort* __restrict__ Gf, const ushort* __restrict__ W3Tf,
    float* __restrict__ out) {
  __shared__ float partial[4][256][4];   // 16KB
  __shared__ float dist_lds[256];

  const int bid = blockIdx.x;
  const int b = bid / 136;
  int q = bid - b*136;
  int it = 0;
  while (q >= 16 - it) { q -= 16 - it; ++it; }
  const int jt = it + q;
  const int i0 = b*256 + it*16, j0 = b*256 + jt*16;
  const int rbi = i0 >> 4, rbj = j0 >> 4;   // fragment row-blocks

  const int tid = threadIdx.x;
  const int lane = tid & 63, w = tid >> 6;
  const int wn = w & 3;      // n-group: ntiles wn*4 .. +4
  const int wp = w >> 2;     // pair-group: ptiles wp*8 .. +8
  const int c15 = lane & 15, hi = lane >> 4;

  if (tid < 256) {
    int pi = tid >> 4, pj = tid & 15;
    const float* pa = &positions[(i0 + pi)*3];
    const float* pb = &positions[(j0 + pj)*3];
    float dx = pa[0]-pb[0], dy = pa[1]-pb[1], dz = pa[2]-pb[2];
    float d2 = dx*dx + dy*dy + dz*dz;
    dist_lds[tid] = d2 > 0.f ? sqrtf(d2) : 0.f;
  }
  __syncthreads();   // dist visible for epilogue; K-loop touches no LDS

  f32x4 acc[4][8];
  #pragma unroll
  for (int at = 0; at < 4; ++at)
    #pragma unroll
    for (int bt = 0; bt < 8; ++bt) { acc[at][bt].x=0.f; acc[at][bt].y=0.f; acc[at][bt].z=0.f; acc[at][bt].w=0.f; }

  #pragma unroll
  for (int kk = 0; kk < 9; ++kk) {
    // A-fragments: coalesced from W3Tf (L2-resident, 147KB)
    short8 afr[4];
    #pragma unroll
    for (int at = 0; at < 4; ++at)
      afr[at] = *reinterpret_cast<const short8*>(
          &W3Tf[((wn*4 + at)*9 + kk)*512 + lane*8]);
    // gj: this lane's j-row octet (row j0+c15, cols kk*32+hi*8..+8)
    union { ushort us[8]; short8 s8; } gj;
    gj.s8 = *reinterpret_cast<const short8*>(&Gf[(rbj*9 + kk)*512 + lane*8]);
    float gjf[8];
    #pragma unroll
    for (int s = 0; s < 8; ++s) gjf[s] = bf2f(gj.us[s]);
    #pragma unroll
    for (int bt = 0; bt < 8; ++bt) {
      int ptg = wp*8 + bt;                 // i-row of this ptile
      union { ushort us[8]; short8 s8; } gi;
      gi.s8 = *reinterpret_cast<const short8*>(
          &Gf[(rbi*9 + kk)*512 + hi*128 + ptg*8]);
      union { unsigned uu[4]; short8 s8; } bb;
      bb.uu[0] = cvtpk(bf2f(gi.us[0])*gjf[0], bf2f(gi.us[1])*gjf[1]);
      bb.uu[1] = cvtpk(bf2f(gi.us[2])*gjf[2], bf2f(gi.us[3])*gjf[3]);
      bb.uu[2] = cvtpk(bf2f(gi.us[4])*gjf[4], bf2f(gi.us[5])*gjf[5]);
      bb.uu[3] = cvtpk(bf2f(gi.us[6])*gjf[6], bf2f(gi.us[7])*gjf[7]);
      acc[0][bt] = __builtin_amdgcn_mfma_f32_16x16x32_bf16(afr[0], bb.s8, acc[0][bt], 0, 0, 0);
      acc[1][bt] = __builtin_amdgcn_mfma_f32_16x16x32_bf16(afr[1], bb.s8, acc[1][bt], 0, 0, 0);
      acc[2][bt] = __builtin_amdgcn_mfma_f32_16x16x32_bf16(afr[2], bb.s8, acc[2][bt], 0, 0, 0);
      acc[3][bt] = __builtin_amdgcn_mfma_f32_16x16x32_bf16(afr[3], bb.s8, acc[3][bt], 0, 0, 0);
    }
  }

  __builtin_amdgcn_sched_barrier(0);   // keep epilogue loads out of K-loop region

  // ---- epilogue: per-at constant loading caps register pressure
  float4 pe[8];
  #pragma unroll
  for (int bt = 0; bt < 8; ++bt) { pe[bt].x=0.f; pe[bt].y=0.f; pe[bt].z=0.f; pe[bt].w=0.f; }
  #pragma unroll
  for (int at = 0; at < 4; ++at) {
    float b3v[4], w30v[4]; float4 w4v[4];
    #pragma unroll
    for (int r = 0; r < 4; ++r) {
      int n = (wn*4 + at)*16 + hi*4 + r;
      b3v[r]  = b3[n];
      w30v[r] = W3[n];                 // W3 row 0 = dist weights
      w4v[r]  = *reinterpret_cast<const float4*>(&W4[n*4]);
    }
    #pragma unroll
    for (int bt = 0; bt < 8; ++bt) {
      float d = dist_lds[(wp*8 + bt)*16 + c15];
      #pragma unroll
      for (int r = 0; r < 4; ++r) {
        float z  = acc[at][bt][r] + d*w30v[r] + b3v[r];
        float rz = fmaxf(z, 0.f);
        pe[bt].x += rz*w4v[r].x; pe[bt].y += rz*w4v[r].y;
        pe[bt].z += rz*w4v[r].z; pe[bt].w += rz*w4v[r].w;
      }
    }
  }
  #pragma unroll
  for (int bt = 0; bt < 8; ++bt) {
    int pair = (wp*8 + bt)*16 + c15;
    float4 p = pe[bt];
    p.x += __shfl_xor(p.x, 16); p.y += __shfl_xor(p.y, 16);
    p.z += __shfl_xor(p.z, 16); p.w += __shfl_xor(p.w, 16);
    p.x += __shfl_xor(p.x, 32); p.y += __shfl_xor(p.y, 32);
    p.z += __shfl_xor(p.z, 32); p.w += __shfl_xor(p.w, 32);
    if (hi == 0) *reinterpret_cast<float4*>(&partial[wn][pair][0]) = p;
  }
  __syncthreads();
  if (tid < 256) {
    int pair = tid;
    float4 v;
    v.x = partial[0][pair][0] + partial[1][pair][0] + partial[2][pair][0] + partial[3][pair][0];
    v.y = partial[0][pair][1] + partial[1][pair][1] + partial[2][pair][1] + partial[3][pair][1];
    v.z = partial[0][pair][2] + partial[1][pair][2] + partial[2][pair][2] + partial[3][pair][2];
    v.w = partial[0][pair][3] + partial[1][pair][3] + partial[2][pair][3] + partial[3][pair][3];
    const float4 bv = *reinterpret_cast<const float4*>(b4);
    v.x += bv.x; v.y += bv.y; v.z += bv.z; v.w += bv.w;
    int il = it*16 + (pair >> 4);       // local i row
    int jl = jt*16 + (pair & 15);       // local j row
    *reinterpret_cast<float4*>(&out[(((size_t)b*256 + il)*256 + jl)*NE]) = v;
    if (it != jt)
      *reinterpret_cast<float4*>(&out[(((size_t)b*256 + jl)*256 + il)*NE]) = v;
  }
}

extern "C" void kernel_launch(void* const* d_in, const int* in_sizes, int n_in,
                              void* d_out, int out_size, void* d_ws, size_t ws_size,
                              hipStream_t stream) {
  const float* latent    = (const float*)d_in[0];
  const float* positions = (const float*)d_in[1];
  const float* atoms     = (const float*)d_in[2];
  const float* W1 = (const float*)d_in[3];
  const float* b1 = (const float*)d_in[4];
  const float* W2 = (const float*)d_in[5];
  const float* b2 = (const float*)d_in[6];
  const float* W3 = (const float*)d_in[7];
  const float* b3 = (const float*)d_in[8];
  const float* W4 = (const float*)d_in[9];
  const float* b4 = (const float*)d_in[10];
  float* out = (float*)d_out;

  char* ws = (char*)d_ws;
  ushort* Gf_ws   = (ushort*)ws;                        // 8*256*288*2 = 1,179,648 B
  ushort* W3Tf_ws = (ushort*)(ws + 1179648);            // 256*288*2   =   147,456 B

  hipLaunchKernelGGL(prep_h_kernel, dim3(256), dim3(256), 0, stream,
                     latent, atoms, W1, b1, W2, b2, Gf_ws);
  hipLaunchKernelGGL(prep_w3t_kernel, dim3(256), dim3(256), 0, stream, W3, W3Tf_ws);
  hipLaunchKernelGGL(edge_main_kernel, dim3(1088), dim3(512), 0, stream,
                     positions, W3, b3, W4, b4, Gf_ws, W3Tf_ws, out);
}

// Round 18
// 100.736 us; speedup vs baseline: 1.8971x; 1.0946x over previous
//
#include <hip/hip_runtime.h>

#define DIM 256
#define NA 16
#define NE 4
#define KTOT 288   // 16 atoms + 256 latent + 16 zero pad (9 chunks of 32)

typedef __attribute__((ext_vector_type(8))) short short8;
typedef __attribute__((ext_vector_type(4))) float f32x4;

static __device__ __forceinline__ ushort f2bf(float f) {
  union { float f; unsigned int u; } v; v.f = f;
  unsigned int r = (v.u + 0x7FFFu + ((v.u >> 16) & 1u)) >> 16;
  return (ushort)r;
}

static __device__ __forceinline__ float bf2f(ushort s) {
  union { unsigned int u; float f; } v; v.u = ((unsigned int)s) << 16;
  return v.f;
}

static __device__ __forceinline__ unsigned cvtpk(float lo, float hi) {
  unsigned r;
  asm("v_cvt_pk_bf16_f32 %0, %1, %2" : "=v"(r) : "v"(lo), "v"(hi));
  return r;
}

// fragment-major index (ushort units): subtile = 16 rows x 32 cols = 1KB,
// laid out [row-block rb][k-chunk kk][oct][r15][e]:
//   idx = ((rb*9 + kk)*4 + oct)*128 + r15*8 + e
static __device__ __forceinline__ int fragIdx(int row, int c) {
  return (((row >> 4)*9 + (c >> 5))*4 + ((c >> 3) & 3))*128 + (row & 15)*8 + (c & 7);
}

// ---------------- prep 1: h = relu(latent@W1+b1)@W2+b2 ; Gf = frag-major [atoms|h|0] bf16
__global__ __launch_bounds__(256) void prep_h_kernel(
    const float* __restrict__ latent, const float* __restrict__ atoms,
    const float* __restrict__ W1, const float* __restrict__ b1,
    const float* __restrict__ W2, const float* __restrict__ b2,
    ushort* __restrict__ Gf) {
  __shared__ float lat[8][DIM];
  __shared__ float t1[8][DIM];
  const int b = blockIdx.x >> 5, i0 = (blockIdx.x & 31) * 8;
  const int k = threadIdx.x;
  #pragma unroll
  for (int r = 0; r < 8; ++r) lat[r][k] = latent[(b*256 + i0 + r) * DIM + k];
  __syncthreads();
  float acc[8];
  #pragma unroll
  for (int r = 0; r < 8; ++r) acc[r] = b1[k];
  for (int c = 0; c < DIM; c += 4) {
    float w0 = W1[(c+0)*DIM + k], w1 = W1[(c+1)*DIM + k];
    float w2 = W1[(c+2)*DIM + k], w3 = W1[(c+3)*DIM + k];
    #pragma unroll
    for (int r = 0; r < 8; ++r) {
      const float4 l4 = *reinterpret_cast<const float4*>(&lat[r][c]);
      acc[r] += l4.x*w0 + l4.y*w1 + l4.z*w2 + l4.w*w3;
    }
  }
  #pragma unroll
  for (int r = 0; r < 8; ++r) t1[r][k] = fmaxf(acc[r], 0.f);
  __syncthreads();
  #pragma unroll
  for (int r = 0; r < 8; ++r) acc[r] = b2[k];
  for (int c = 0; c < DIM; c += 4) {
    float w0 = W2[(c+0)*DIM + k], w1 = W2[(c+1)*DIM + k];
    float w2 = W2[(c+2)*DIM + k], w3 = W2[(c+3)*DIM + k];
    #pragma unroll
    for (int r = 0; r < 8; ++r) {
      const float4 l4 = *reinterpret_cast<const float4*>(&t1[r][c]);
      acc[r] += l4.x*w0 + l4.y*w1 + l4.z*w2 + l4.w*w3;
    }
  }
  #pragma unroll
  for (int r = 0; r < 8; ++r) {
    int row = b*256 + i0 + r;
    Gf[fragIdx(row, NA + k)] = f2bf(acc[r]);
  }
  if (k < NA) {
    #pragma unroll
    for (int r = 0; r < 8; ++r) {
      int row = b*256 + i0 + r;
      Gf[fragIdx(row, k)] = f2bf(atoms[row*NA + k]);
      Gf[fragIdx(row, 272 + k)] = 0;
    }
  }
}

// ---------------- prep 2: W3Tf frag-major: value(n,c) = bf16(W3[1+c][n]), pad 0
__global__ __launch_bounds__(256) void prep_w3t_kernel(
    const float* __restrict__ W3, ushort* __restrict__ W3Tf) {
  const int n = blockIdx.x, c = threadIdx.x;
  W3Tf[fragIdx(n, c)] = (c < 272) ? f2bf(W3[(1+c)*DIM + n]) : (ushort)0;
  if (c < 32) {
    int c2 = 256 + c;
    W3Tf[fragIdx(n, c2)] = (c2 < 272) ? f2bf(W3[(1+c2)*DIM + n]) : (ushort)0;
  }
}

// ---------------- main: one WG per (b, it<=jt) pair-tile (1088 WGs, 512 thr).
// Barrier-free K-loop; G rows pre-staged in LDS (18.4KB, ONE barrier):
//   A-frag: W3Tf from L2, coalesced + address-independent (prefetchable).
//   B-frag: built in-register from LDS gi/gj (ds_read ~60cyc, hidden).
__global__ __attribute__((amdgpu_flat_work_group_size(512,512), amdgpu_waves_per_eu(2,2)))
void edge_main_kernel(
    const float* __restrict__ positions,
    const float* __restrict__ W3, const float* __restrict__ b3,
    const float* __restrict__ W4, const float* __restrict__ b4,
    const ushort* __restrict__ Gf, const ushort* __restrict__ W3Tf,
    float* __restrict__ out) {
  __shared__ ushort gi_lds[4608];        // i row-block, frag-major (9.2KB)
  __shared__ ushort gj_lds[4608];        // j row-block, frag-major (9.2KB)
  __shared__ float partial[4][256][4];   // 16KB
  __shared__ float dist_lds[256];

  const int bid = blockIdx.x;
  const int b = bid / 136;
  int q = bid - b*136;
  int it = 0;
  while (q >= 16 - it) { q -= 16 - it; ++it; }
  const int jt = it + q;
  const int i0 = b*256 + it*16, j0 = b*256 + jt*16;
  const int rbi = i0 >> 4, rbj = j0 >> 4;   // fragment row-blocks

  const int tid = threadIdx.x;
  const int lane = tid & 63, w = tid >> 6;
  const int wn = w & 3;      // n-group: ntiles wn*4 .. +4
  const int wp = w >> 2;     // pair-group: ptiles wp*8 .. +8
  const int c15 = lane & 15, hi = lane >> 4;

  // ---- stage the two G row-blocks into LDS (contiguous 9216B each)
  {
    const uint4* srcI = reinterpret_cast<const uint4*>(Gf + (size_t)rbi*4608);
    const uint4* srcJ = reinterpret_cast<const uint4*>(Gf + (size_t)rbj*4608);
    uint4* dI = reinterpret_cast<uint4*>(gi_lds);
    uint4* dJ = reinterpret_cast<uint4*>(gj_lds);
    dI[tid] = srcI[tid];
    dJ[tid] = srcJ[tid];
    if (tid < 64) { dI[512+tid] = srcI[512+tid]; dJ[512+tid] = srcJ[512+tid]; }
  }
  if (tid < 256) {
    int pi = tid >> 4, pj = tid & 15;
    const float* pa = &positions[(i0 + pi)*3];
    const float* pb = &positions[(j0 + pj)*3];
    float dx = pa[0]-pb[0], dy = pa[1]-pb[1], dz = pa[2]-pb[2];
    float d2 = dx*dx + dy*dy + dz*dz;
    dist_lds[tid] = d2 > 0.f ? sqrtf(d2) : 0.f;
  }
  __syncthreads();   // g blocks + dist visible; no more barriers until epilogue

  f32x4 acc[4][8];
  #pragma unroll
  for (int at = 0; at < 4; ++at)
    #pragma unroll
    for (int bt = 0; bt < 8; ++bt) { acc[at][bt].x=0.f; acc[at][bt].y=0.f; acc[at][bt].z=0.f; acc[at][bt].w=0.f; }

  #pragma unroll
  for (int kk = 0; kk < 9; ++kk) {
    // A-fragments: coalesced from W3Tf (L2-resident; addresses independent)
    short8 afr[4];
    #pragma unroll
    for (int at = 0; at < 4; ++at)
      afr[at] = *reinterpret_cast<const short8*>(
          &W3Tf[((wn*4 + at)*9 + kk)*512 + lane*8]);
    // gj: this lane's j-row octet from LDS (contiguous 1KB per wave)
    union { ushort us[8]; short8 s8; } gj;
    gj.s8 = *reinterpret_cast<const short8*>(&gj_lds[kk*512 + lane*8]);
    float gjf[8];
    #pragma unroll
    for (int s = 0; s < 8; ++s) gjf[s] = bf2f(gj.us[s]);
    #pragma unroll
    for (int bt = 0; bt < 8; ++bt) {
      int ptg = wp*8 + bt;                 // i-row of this ptile
      union { ushort us[8]; short8 s8; } gi;
      gi.s8 = *reinterpret_cast<const short8*>(
          &gi_lds[kk*512 + hi*128 + ptg*8]);
      union { unsigned uu[4]; short8 s8; } bb;
      bb.uu[0] = cvtpk(bf2f(gi.us[0])*gjf[0], bf2f(gi.us[1])*gjf[1]);
      bb.uu[1] = cvtpk(bf2f(gi.us[2])*gjf[2], bf2f(gi.us[3])*gjf[3]);
      bb.uu[2] = cvtpk(bf2f(gi.us[4])*gjf[4], bf2f(gi.us[5])*gjf[5]);
      bb.uu[3] = cvtpk(bf2f(gi.us[6])*gjf[6], bf2f(gi.us[7])*gjf[7]);
      acc[0][bt] = __builtin_amdgcn_mfma_f32_16x16x32_bf16(afr[0], bb.s8, acc[0][bt], 0, 0, 0);
      acc[1][bt] = __builtin_amdgcn_mfma_f32_16x16x32_bf16(afr[1], bb.s8, acc[1][bt], 0, 0, 0);
      acc[2][bt] = __builtin_amdgcn_mfma_f32_16x16x32_bf16(afr[2], bb.s8, acc[2][bt], 0, 0, 0);
      acc[3][bt] = __builtin_amdgcn_mfma_f32_16x16x32_bf16(afr[3], bb.s8, acc[3][bt], 0, 0, 0);
    }
  }

  __builtin_amdgcn_sched_barrier(0);   // keep epilogue loads out of K-loop region

  // ---- epilogue: per-at constant loading caps register pressure
  float4 pe[8];
  #pragma unroll
  for (int bt = 0; bt < 8; ++bt) { pe[bt].x=0.f; pe[bt].y=0.f; pe[bt].z=0.f; pe[bt].w=0.f; }
  #pragma unroll
  for (int at = 0; at < 4; ++at) {
    float b3v[4], w30v[4]; float4 w4v[4];
    #pragma unroll
    for (int r = 0; r < 4; ++r) {
      int n = (wn*4 + at)*16 + hi*4 + r;
      b3v[r]  = b3[n];
      w30v[r] = W3[n];                 // W3 row 0 = dist weights
      w4v[r]  = *reinterpret_cast<const float4*>(&W4[n*4]);
    }
    #pragma unroll
    for (int bt = 0; bt < 8; ++bt) {
      float d = dist_lds[(wp*8 + bt)*16 + c15];
      #pragma unroll
      for (int r = 0; r < 4; ++r) {
        float z  = acc[at][bt][r] + d*w30v[r] + b3v[r];
        float rz = fmaxf(z, 0.f);
        pe[bt].x += rz*w4v[r].x; pe[bt].y += rz*w4v[r].y;
        pe[bt].z += rz*w4v[r].z; pe[bt].w += rz*w4v[r].w;
      }
    }
  }
  #pragma unroll
  for (int bt = 0; bt < 8; ++bt) {
    int pair = (wp*8 + bt)*16 + c15;
    float4 p = pe[bt];
    p.x += __shfl_xor(p.x, 16); p.y += __shfl_xor(p.y, 16);
    p.z += __shfl_xor(p.z, 16); p.w += __shfl_xor(p.w, 16);
    p.x += __shfl_xor(p.x, 32); p.y += __shfl_xor(p.y, 32);
    p.z += __shfl_xor(p.z, 32); p.w += __shfl_xor(p.w, 32);
    if (hi == 0) *reinterpret_cast<float4*>(&partial[wn][pair][0]) = p;
  }
  __syncthreads();
  if (tid < 256) {
    int pair = tid;
    float4 v;
    v.x = partial[0][pair][0] + partial[1][pair][0] + partial[2][pair][0] + partial[3][pair][0];
    v.y = partial[0][pair][1] + partial[1][pair][1] + partial[2][pair][1] + partial[3][pair][1];
    v.z = partial[0][pair][2] + partial[1][pair][2] + partial[2][pair][2] + partial[3][pair][2];
    v.w = partial[0][pair][3] + partial[1][pair][3] + partial[2][pair][3] + partial[3][pair][3];
    const float4 bv = *reinterpret_cast<const float4*>(b4);
    v.x += bv.x; v.y += bv.y; v.z += bv.z; v.w += bv.w;
    int il = it*16 + (pair >> 4);       // local i row
    int jl = jt*16 + (pair & 15);       // local j row
    *reinterpret_cast<float4*>(&out[(((size_t)b*256 + il)*256 + jl)*NE]) = v;
    if (it != jt)
      *reinterpret_cast<float4*>(&out[(((size_t)b*256 + jl)*256 + il)*NE]) = v;
  }
}

extern "C" void kernel_launch(void* const* d_in, const int* in_sizes, int n_in,
                              void* d_out, int out_size, void* d_ws, size_t ws_size,
                              hipStream_t stream) {
  const float* latent    = (const float*)d_in[0];
  const float* positions = (const float*)d_in[1];
  const float* atoms     = (const float*)d_in[2];
  const float* W1 = (const float*)d_in[3];
  const float* b1 = (const float*)d_in[4];
  const float* W2 = (const float*)d_in[5];
  const float* b2 = (const float*)d_in[6];
  const float* W3 = (const float*)d_in[7];
  const float* b3 = (const float*)d_in[8];
  const float* W4 = (const float*)d_in[9];
  const float* b4 = (const float*)d_in[10];
  float* out = (float*)d_out;

  char* ws = (char*)d_ws;
  ushort* Gf_ws   = (ushort*)ws;                        // 8*256*288*2 = 1,179,648 B
  ushort* W3Tf_ws = (ushort*)(ws + 1179648);            // 256*288*2   =   147,456 B

  hipLaunchKernelGGL(prep_h_kernel, dim3(256), dim3(256), 0, stream,
                     latent, atoms, W1, b1, W2, b2, Gf_ws);
  hipLaunchKernelGGL(prep_w3t_kernel, dim3(256), dim3(256), 0, stream, W3, W3Tf_ws);
  hipLaunchKernelGGL(edge_main_kernel, dim3(1088), dim3(512), 0, stream,
                     positions, W3, b3, W4, b4, Gf_ws, W3Tf_ws, out);
}

// Round 19
// 100.335 us; speedup vs baseline: 1.9047x; 1.0040x over previous
//
#include <hip/hip_runtime.h>

#define DIM 256
#define NA 16
#define NE 4
#define KTOT 288   // 16 atoms + 256 latent + 16 zero pad (9 chunks of 32)

typedef __attribute__((ext_vector_type(8))) short short8;
typedef __attribute__((ext_vector_type(4))) float f32x4;

static __device__ __forceinline__ ushort f2bf(float f) {
  union { float f; unsigned int u; } v; v.f = f;
  unsigned int r = (v.u + 0x7FFFu + ((v.u >> 16) & 1u)) >> 16;
  return (ushort)r;
}

static __device__ __forceinline__ float bf2f(ushort s) {
  union { unsigned int u; float f; } v; v.u = ((unsigned int)s) << 16;
  return v.f;
}

static __device__ __forceinline__ unsigned cvtpk(float lo, float hi) {
  unsigned r;
  asm("v_cvt_pk_bf16_f32 %0, %1, %2" : "=v"(r) : "v"(lo), "v"(hi));
  return r;
}

// fragment-major index (ushort units): subtile = 16 rows x 32 cols = 1KB,
// laid out [row-block rb][k-chunk kk][oct][r15][e]:
//   idx = ((rb*9 + kk)*4 + oct)*128 + r15*8 + e
static __device__ __forceinline__ int fragIdx(int row, int c) {
  return (((row >> 4)*9 + (c >> 5))*4 + ((c >> 3) & 3))*128 + (row & 15)*8 + (c & 7);
}

// ---------------- prep 1: h = relu(latent@W1+b1)@W2+b2 ; Gf = frag-major [atoms|h|0] bf16
__global__ __launch_bounds__(256) void prep_h_kernel(
    const float* __restrict__ latent, const float* __restrict__ atoms,
    const float* __restrict__ W1, const float* __restrict__ b1,
    const float* __restrict__ W2, const float* __restrict__ b2,
    ushort* __restrict__ Gf) {
  __shared__ float lat[8][DIM];
  __shared__ float t1[8][DIM];
  const int b = blockIdx.x >> 5, i0 = (blockIdx.x & 31) * 8;
  const int k = threadIdx.x;
  #pragma unroll
  for (int r = 0; r < 8; ++r) lat[r][k] = latent[(b*256 + i0 + r) * DIM + k];
  __syncthreads();
  float acc[8];
  #pragma unroll
  for (int r = 0; r < 8; ++r) acc[r] = b1[k];
  for (int c = 0; c < DIM; c += 4) {
    float w0 = W1[(c+0)*DIM + k], w1 = W1[(c+1)*DIM + k];
    float w2 = W1[(c+2)*DIM + k], w3 = W1[(c+3)*DIM + k];
    #pragma unroll
    for (int r = 0; r < 8; ++r) {
      const float4 l4 = *reinterpret_cast<const float4*>(&lat[r][c]);
      acc[r] += l4.x*w0 + l4.y*w1 + l4.z*w2 + l4.w*w3;
    }
  }
  #pragma unroll
  for (int r = 0; r < 8; ++r) t1[r][k] = fmaxf(acc[r], 0.f);
  __syncthreads();
  #pragma unroll
  for (int r = 0; r < 8; ++r) acc[r] = b2[k];
  for (int c = 0; c < DIM; c += 4) {
    float w0 = W2[(c+0)*DIM + k], w1 = W2[(c+1)*DIM + k];
    float w2 = W2[(c+2)*DIM + k], w3 = W2[(c+3)*DIM + k];
    #pragma unroll
    for (int r = 0; r < 8; ++r) {
      const float4 l4 = *reinterpret_cast<const float4*>(&t1[r][c]);
      acc[r] += l4.x*w0 + l4.y*w1 + l4.z*w2 + l4.w*w3;
    }
  }
  #pragma unroll
  for (int r = 0; r < 8; ++r) {
    int row = b*256 + i0 + r;
    Gf[fragIdx(row, NA + k)] = f2bf(acc[r]);
  }
  if (k < NA) {
    #pragma unroll
    for (int r = 0; r < 8; ++r) {
      int row = b*256 + i0 + r;
      Gf[fragIdx(row, k)] = f2bf(atoms[row*NA + k]);
      Gf[fragIdx(row, 272 + k)] = 0;
    }
  }
}

// ---------------- prep 2: W3Tf frag-major: value(n,c) = bf16(W3[1+c][n]), pad 0
__global__ __launch_bounds__(256) void prep_w3t_kernel(
    const float* __restrict__ W3, ushort* __restrict__ W3Tf) {
  const int n = blockIdx.x, c = threadIdx.x;
  W3Tf[fragIdx(n, c)] = (c < 272) ? f2bf(W3[(1+c)*DIM + n]) : (ushort)0;
  if (c < 32) {
    int c2 = 256 + c;
    W3Tf[fragIdx(n, c2)] = (c2 < 272) ? f2bf(W3[(1+c2)*DIM + n]) : (ushort)0;
  }
}

// ---------------- main: one WG per (b, it<=jt, i-quarter) = 8*136*4 = 4352 WGs.
// 4-WAVE WG (256 thr) = 1 wave/SIMD; waves_per_eu(3,3) caps regs at ~168 so
// THREE independent WGs co-reside per SIMD -> latency of one hides under the
// others (the R13/R18 2-wave lockstep ceiling).
// Quarter tile: 64 pairs (4 i-rows x 16 j) x 256 n x K288.
// Wave w: ntiles w*4..w*4+4 (acc[4][4] = 64 AGPR).
// A-frag: W3Tf from L2 (coalesced); B-frag in-register from LDS gi/gj.
__global__ __attribute__((amdgpu_flat_work_group_size(256,256), amdgpu_waves_per_eu(3,3)))
void edge_main_kernel(
    const float* __restrict__ positions,
    const float* __restrict__ W3, const float* __restrict__ b3,
    const float* __restrict__ W4, const float* __restrict__ b4,
    const ushort* __restrict__ Gf, const ushort* __restrict__ W3Tf,
    float* __restrict__ out) {
  __shared__ ushort gi_lds[4608];        // i row-block, frag-major (9.2KB)
  __shared__ ushort gj_lds[4608];        // j row-block, frag-major (9.2KB)
  __shared__ float partial[4][64][4];    // 4KB
  __shared__ float dist_lds[64];

  const int bid = blockIdx.x;
  const int b = bid / 544;               // 136 tiles * 4 quarters per b
  int rem = bid - b*544;
  const int qq4 = rem & 3;               // i-quarter: rows [qq4*4, qq4*4+4)
  int q = rem >> 2;
  int it = 0;
  while (q >= 16 - it) { q -= 16 - it; ++it; }
  const int jt = it + q;
  const int i0 = b*256 + it*16, j0 = b*256 + jt*16;
  const int rbi = i0 >> 4, rbj = j0 >> 4;

  const int tid = threadIdx.x;
  const int lane = tid & 63, w = tid >> 6;   // w = n-group (ntiles w*4..+4)
  const int c15 = lane & 15, hi = lane >> 4;

  // ---- stage the two G row-blocks into LDS (contiguous 9216B each)
  {
    const uint4* srcI = reinterpret_cast<const uint4*>(Gf + (size_t)rbi*4608);
    const uint4* srcJ = reinterpret_cast<const uint4*>(Gf + (size_t)rbj*4608);
    uint4* dI = reinterpret_cast<uint4*>(gi_lds);
    uint4* dJ = reinterpret_cast<uint4*>(gj_lds);
    dI[tid] = srcI[tid];
    dJ[tid] = srcJ[tid];
    dI[256+tid] = srcI[256+tid];
    dJ[256+tid] = srcJ[256+tid];
    if (tid < 64) { dI[512+tid] = srcI[512+tid]; dJ[512+tid] = srcJ[512+tid]; }
  }
  if (tid < 64) {
    int pi = tid >> 4, pj = tid & 15;
    const float* pa = &positions[(i0 + qq4*4 + pi)*3];
    const float* pb = &positions[(j0 + pj)*3];
    float dx = pa[0]-pb[0], dy = pa[1]-pb[1], dz = pa[2]-pb[2];
    float d2 = dx*dx + dy*dy + dz*dz;
    dist_lds[tid] = d2 > 0.f ? sqrtf(d2) : 0.f;
  }

  f32x4 acc[4][4];
  #pragma unroll
  for (int at = 0; at < 4; ++at)
    #pragma unroll
    for (int bt = 0; bt < 4; ++bt) { acc[at][bt].x=0.f; acc[at][bt].y=0.f; acc[at][bt].z=0.f; acc[at][bt].w=0.f; }

  __syncthreads();   // g blocks + dist visible; no more barriers until epilogue

  #pragma unroll
  for (int kk = 0; kk < 9; ++kk) {
    // gj: this lane's j-row octet from LDS (contiguous 1KB per wave)
    union { ushort us[8]; short8 s8; } gj;
    gj.s8 = *reinterpret_cast<const short8*>(&gj_lds[kk*512 + lane*8]);
    float gjf[8];
    #pragma unroll
    for (int s = 0; s < 8; ++s) gjf[s] = bf2f(gj.us[s]);
    // build all 4 B-fragments (bb persists across the at loop; never rebuilt)
    short8 bbv[4];
    #pragma unroll
    for (int bt = 0; bt < 4; ++bt) {
      union { ushort us[8]; short8 s8; } gi;
      gi.s8 = *reinterpret_cast<const short8*>(
          &gi_lds[kk*512 + hi*128 + (qq4*4 + bt)*8]);
      union { unsigned uu[4]; short8 s8; } bb;
      bb.uu[0] = cvtpk(bf2f(gi.us[0])*gjf[0], bf2f(gi.us[1])*gjf[1]);
      bb.uu[1] = cvtpk(bf2f(gi.us[2])*gjf[2], bf2f(gi.us[3])*gjf[3]);
      bb.uu[2] = cvtpk(bf2f(gi.us[4])*gjf[4], bf2f(gi.us[5])*gjf[5]);
      bb.uu[3] = cvtpk(bf2f(gi.us[6])*gjf[6], bf2f(gi.us[7])*gjf[7]);
      bbv[bt] = bb.s8;
    }
    // A-fragments from W3Tf (L2), one at a time (register-lean)
    #pragma unroll
    for (int at = 0; at < 4; ++at) {
      short8 af = *reinterpret_cast<const short8*>(
          &W3Tf[((w*4 + at)*9 + kk)*512 + lane*8]);
      acc[at][0] = __builtin_amdgcn_mfma_f32_16x16x32_bf16(af, bbv[0], acc[at][0], 0, 0, 0);
      acc[at][1] = __builtin_amdgcn_mfma_f32_16x16x32_bf16(af, bbv[1], acc[at][1], 0, 0, 0);
      acc[at][2] = __builtin_amdgcn_mfma_f32_16x16x32_bf16(af, bbv[2], acc[at][2], 0, 0, 0);
      acc[at][3] = __builtin_amdgcn_mfma_f32_16x16x32_bf16(af, bbv[3], acc[at][3], 0, 0, 0);
    }
  }

  __builtin_amdgcn_sched_barrier(0);   // keep epilogue loads out of K-loop region

  // ---- epilogue: per-at constant loading caps register pressure
  float4 pe[4];
  #pragma unroll
  for (int bt = 0; bt < 4; ++bt) { pe[bt].x=0.f; pe[bt].y=0.f; pe[bt].z=0.f; pe[bt].w=0.f; }
  #pragma unroll
  for (int at = 0; at < 4; ++at) {
    float b3v[4], w30v[4]; float4 w4v[4];
    #pragma unroll
    for (int r = 0; r < 4; ++r) {
      int n = (w*4 + at)*16 + hi*4 + r;
      b3v[r]  = b3[n];
      w30v[r] = W3[n];                 // W3 row 0 = dist weights
      w4v[r]  = *reinterpret_cast<const float4*>(&W4[n*4]);
    }
    #pragma unroll
    for (int bt = 0; bt < 4; ++bt) {
      float d = dist_lds[bt*16 + c15];
      #pragma unroll
      for (int r = 0; r < 4; ++r) {
        float z  = acc[at][bt][r] + d*w30v[r] + b3v[r];
        float rz = fmaxf(z, 0.f);
        pe[bt].x += rz*w4v[r].x; pe[bt].y += rz*w4v[r].y;
        pe[bt].z += rz*w4v[r].z; pe[bt].w += rz*w4v[r].w;
      }
    }
  }
  #pragma unroll
  for (int bt = 0; bt < 4; ++bt) {
    int pair = bt*16 + c15;
    float4 p = pe[bt];
    p.x += __shfl_xor(p.x, 16); p.y += __shfl_xor(p.y, 16);
    p.z += __shfl_xor(p.z, 16); p.w += __shfl_xor(p.w, 16);
    p.x += __shfl_xor(p.x, 32); p.y += __shfl_xor(p.y, 32);
    p.z += __shfl_xor(p.z, 32); p.w += __shfl_xor(p.w, 32);
    if (hi == 0) *reinterpret_cast<float4*>(&partial[w][pair][0]) = p;
  }
  __syncthreads();
  if (tid < 64) {
    int pair = tid;
    float4 v;
    v.x = partial[0][pair][0] + partial[1][pair][0] + partial[2][pair][0] + partial[3][pair][0];
    v.y = partial[0][pair][1] + partial[1][pair][1] + partial[2][pair][1] + partial[3][pair][1];
    v.z = partial[0][pair][2] + partial[1][pair][2] + partial[2][pair][2] + partial[3][pair][2];
    v.w = partial[0][pair][3] + partial[1][pair][3] + partial[2][pair][3] + partial[3][pair][3];
    const float4 bv = *reinterpret_cast<const float4*>(b4);
    v.x += bv.x; v.y += bv.y; v.z += bv.z; v.w += bv.w;
    int il = it*16 + qq4*4 + (pair >> 4);   // local i row
    int jl = jt*16 + (pair & 15);           // local j row
    *reinterpret_cast<float4*>(&out[(((size_t)b*256 + il)*256 + jl)*NE]) = v;
    if (it != jt)
      *reinterpret_cast<float4*>(&out[(((size_t)b*256 + jl)*256 + il)*NE]) = v;
  }
}

extern "C" void kernel_launch(void* const* d_in, const int* in_sizes, int n_in,
                              void* d_out, int out_size, void* d_ws, size_t ws_size,
                              hipStream_t stream) {
  const float* latent    = (const float*)d_in[0];
  const float* positions = (const float*)d_in[1];
  const float* atoms     = (const float*)d_in[2];
  const float* W1 = (const float*)d_in[3];
  const float* b1 = (const float*)d_in[4];
  const float* W2 = (const float*)d_in[5];
  const float* b2 = (const float*)d_in[6];
  const float* W3 = (const float*)d_in[7];
  const float* b3 = (const float*)d_in[8];
  const float* W4 = (const float*)d_in[9];
  const float* b4 = (const float*)d_in[10];
  float* out = (float*)d_out;

  char* ws = (char*)d_ws;
  ushort* Gf_ws   = (ushort*)ws;                        // 8*256*288*2 = 1,179,648 B
  ushort* W3Tf_ws = (ushort*)(ws + 1179648);            // 256*288*2   =   147,456 B

  hipLaunchKernelGGL(prep_h_kernel, dim3(256), dim3(256), 0, stream,
                     latent, atoms, W1, b1, W2, b2, Gf_ws);
  hipLaunchKernelGGL(prep_w3t_kernel, dim3(256), dim3(256), 0, stream, W3, W3Tf_ws);
  hipLaunchKernelGGL(edge_main_kernel, dim3(4352), dim3(256), 0, stream,
                     positions, W3, b3, W4, b4, Gf_ws, W3Tf_ws, out);
}